// Round 3
// baseline (766.562 us; speedup 1.0000x reference)
//
#include <hip/hip_runtime.h>
#include <hip/hip_bf16.h>
#include <math.h>

// Problem constants
#define B_SZ   4096
#define NCAND  32
#define DIN    256
#define E_SZ   128
#define H_SZ   512
#define VOCAB  32
#define LN_EPS 1e-5f

static __device__ __forceinline__ float sigmoidf_(float x) {
    return 1.0f / (1.0f + expf(-x));
}

// ---------------------------------------------------------------------------
// Kernel 1: attention — per b: keys = co[b] @ Wk + bk (32x128), scores,
// softmax over 32, context; writes rnn_input[b] = [context|sender|prev_msg]
// All fp32.
// ---------------------------------------------------------------------------
__global__ __launch_bounds__(256)
void attn_kernel(const float* __restrict__ co,    // rows x 32 x 256
                 const float* __restrict__ Wk,    // 256 x 128
                 const float* __restrict__ bk,    // 128
                 const float* __restrict__ snd,   // rows x 128
                 const float* __restrict__ pmsg,  // rows x 128
                 float* __restrict__ rnn_in)      // rows x 384
{
    __shared__ float s_co[NCAND][DIN];      // 32 KB
    __shared__ float s_keys[NCAND][132];    // padded row
    __shared__ float s_snd[E_SZ];
    __shared__ float s_scores[NCAND];
    __shared__ float s_w[NCAND];

    const int b   = blockIdx.x;
    const int tid = threadIdx.x;

    {
        const float4* cop = (const float4*)(co + (size_t)b * NCAND * DIN);
        float4* s4 = (float4*)&s_co[0][0];
        #pragma unroll
        for (int i = 0; i < 8; ++i) s4[tid + i * 256] = cop[tid + i * 256];
        if (tid < E_SZ) s_snd[tid] = snd[(size_t)b * E_SZ + tid];
    }
    __syncthreads();

    // keys: 256 threads = 32 e-groups(x4) * 8 n-groups(x4); 4x4 microtile
    {
        const int eg = tid & 31, ng = tid >> 5;
        const int e0 = eg * 4, n0 = ng * 4;
        float acc[4][4] = {};
        for (int k = 0; k < DIN; k += 4) {
            float4 w0 = *(const float4*)(Wk + (size_t)(k + 0) * E_SZ + e0);
            float4 w1 = *(const float4*)(Wk + (size_t)(k + 1) * E_SZ + e0);
            float4 w2 = *(const float4*)(Wk + (size_t)(k + 2) * E_SZ + e0);
            float4 w3 = *(const float4*)(Wk + (size_t)(k + 3) * E_SZ + e0);
            float wr[4][4] = {{w0.x,w0.y,w0.z,w0.w},{w1.x,w1.y,w1.z,w1.w},
                              {w2.x,w2.y,w2.z,w2.w},{w3.x,w3.y,w3.z,w3.w}};
            #pragma unroll
            for (int i = 0; i < 4; ++i) {
                float4 c4 = *(const float4*)&s_co[n0 + i][k];
                float cc[4] = {c4.x, c4.y, c4.z, c4.w};
                #pragma unroll
                for (int kk = 0; kk < 4; ++kk)
                    #pragma unroll
                    for (int j = 0; j < 4; ++j)
                        acc[i][j] = fmaf(cc[kk], wr[kk][j], acc[i][j]);
            }
        }
        float4 bkv = *(const float4*)(bk + e0);
        #pragma unroll
        for (int i = 0; i < 4; ++i) {
            float4 o;
            o.x = acc[i][0] + bkv.x;
            o.y = acc[i][1] + bkv.y;
            o.z = acc[i][2] + bkv.z;
            o.w = acc[i][3] + bkv.w;
            *(float4*)&s_keys[n0 + i][e0] = o;
        }
    }
    __syncthreads();

    // scores[n] = dot(keys[n], sender) — 8 lanes per n
    {
        const int n = tid >> 3, part = tid & 7;
        float sc = 0.f;
        #pragma unroll
        for (int q = 0; q < 4; ++q) {
            float4 kv = *(const float4*)&s_keys[n][part * 16 + q * 4];
            float4 sv = *(const float4*)&s_snd[part * 16 + q * 4];
            sc += kv.x * sv.x + kv.y * sv.y + kv.z * sv.z + kv.w * sv.w;
        }
        #pragma unroll
        for (int m = 4; m; m >>= 1) sc += __shfl_xor(sc, m);
        if (part == 0) s_scores[n] = sc;
    }
    __syncthreads();

    if (tid < NCAND) {
        float s  = s_scores[tid];
        float mx = s;
        #pragma unroll
        for (int m = 16; m; m >>= 1) mx = fmaxf(mx, __shfl_xor(mx, m));
        float e = expf(s - mx);
        float sum = e;
        #pragma unroll
        for (int m = 16; m; m >>= 1) sum += __shfl_xor(sum, m);
        s_w[tid] = e / sum;
    }
    __syncthreads();

    if (tid < E_SZ) {
        float ctx = 0.f;
        #pragma unroll
        for (int n = 0; n < NCAND; ++n) ctx = fmaf(s_w[n], s_keys[n][tid], ctx);
        float* rb = rnn_in + (size_t)b * 384;
        rb[tid]           = ctx;
        rb[E_SZ + tid]    = s_snd[tid];
        rb[2*E_SZ + tid]  = pmsg[(size_t)b * E_SZ + tid];
    }
}

// ---------------------------------------------------------------------------
// Kernel 2: fp32 GEMM C = A(MxK) * B(KxN) + bias, row-major, 64x64x16 tiles
// ---------------------------------------------------------------------------
__global__ __launch_bounds__(256)
void gemm_bias_kernel(const float* __restrict__ A, const float* __restrict__ Bm,
                      const float* __restrict__ bias, float* __restrict__ C,
                      int M, int N, int K)
{
    __shared__ float As[16][68];
    __shared__ float Bs[16][64];

    const int tid = threadIdx.x;
    const int bm = blockIdx.y * 64;
    const int bn = blockIdx.x * 64;
    const int tx = tid & 15;
    const int ty = tid >> 4;
    const int m0 = ty * 4, n0 = tx * 4;

    const int arow = tid >> 2;
    const int acol = (tid & 3) * 4;
    const int brow = tid >> 4;
    const int bcol = (tid & 15) * 4;

    float acc[4][4] = {};

    for (int k0 = 0; k0 < K; k0 += 16) {
        float4 a4 = *(const float4*)(A  + (size_t)(bm + arow) * K + (k0 + acol));
        float4 b4 = *(const float4*)(Bm + (size_t)(k0 + brow) * N + (bn + bcol));
        As[acol + 0][arow] = a4.x;
        As[acol + 1][arow] = a4.y;
        As[acol + 2][arow] = a4.z;
        As[acol + 3][arow] = a4.w;
        *(float4*)&Bs[brow][bcol] = b4;
        __syncthreads();
        #pragma unroll
        for (int k = 0; k < 16; ++k) {
            float4 av = *(const float4*)&As[k][m0];
            float4 bv = *(const float4*)&Bs[k][n0];
            float aa[4] = {av.x, av.y, av.z, av.w};
            float bb[4] = {bv.x, bv.y, bv.z, bv.w};
            #pragma unroll
            for (int i = 0; i < 4; ++i)
                #pragma unroll
                for (int j = 0; j < 4; ++j)
                    acc[i][j] = fmaf(aa[i], bb[j], acc[i][j]);
        }
        __syncthreads();
    }

    const float4 bv = *(const float4*)(bias + bn + n0);
    #pragma unroll
    for (int i = 0; i < 4; ++i) {
        float4 o;
        o.x = acc[i][0] + bv.x;
        o.y = acc[i][1] + bv.y;
        o.z = acc[i][2] + bv.z;
        o.w = acc[i][3] + bv.w;
        *(float4*)(C + (size_t)(bm + m0 + i) * N + bn + n0) = o;
    }
}

// ---------------------------------------------------------------------------
// Kernel 3: per-row LN-GRU combine. Writes h_new (fp32) directly into the
// d_out new_hidden region.
// ---------------------------------------------------------------------------
__global__ __launch_bounds__(256)
void gru_combine_kernel(const float* __restrict__ gx, const float* __restrict__ gh,
                        const float* __restrict__ cx, const float* __restrict__ ch,
                        const float* __restrict__ hprev,
                        float* __restrict__ hout)
{
    const int b    = blockIdx.x;
    const int tid  = threadIdx.x;
    const int lane = tid & 63, wv = tid >> 6;

    __shared__ float s_part[4][8];
    __shared__ float s_gates[1024];

    const float* gxb = gx + (size_t)b * 1024;
    const float* ghb = gh + (size_t)b * 1024;
    const float* cxb = cx + (size_t)b * 512;
    const float* chb = ch + (size_t)b * 512;

    const float4 gx4 = *(const float4*)(gxb + tid * 4);
    const float4 gh4 = *(const float4*)(ghb + tid * 4);
    const float2 cx2 = *(const float2*)(cxb + tid * 2);
    const float2 ch2 = *(const float2*)(chb + tid * 2);

    float v[8];
    v[0] = gx4.x + gx4.y + gx4.z + gx4.w;
    v[1] = gx4.x*gx4.x + gx4.y*gx4.y + gx4.z*gx4.z + gx4.w*gx4.w;
    v[2] = gh4.x + gh4.y + gh4.z + gh4.w;
    v[3] = gh4.x*gh4.x + gh4.y*gh4.y + gh4.z*gh4.z + gh4.w*gh4.w;
    v[4] = cx2.x + cx2.y;
    v[5] = cx2.x*cx2.x + cx2.y*cx2.y;
    v[6] = ch2.x + ch2.y;
    v[7] = ch2.x*ch2.x + ch2.y*ch2.y;

    #pragma unroll
    for (int i = 0; i < 8; ++i)
        #pragma unroll
        for (int m = 32; m; m >>= 1) v[i] += __shfl_xor(v[i], m);

    if (lane == 0) {
        #pragma unroll
        for (int i = 0; i < 8; ++i) s_part[wv][i] = v[i];
    }
    __syncthreads();

    float t[8];
    #pragma unroll
    for (int i = 0; i < 8; ++i)
        t[i] = s_part[0][i] + s_part[1][i] + s_part[2][i] + s_part[3][i];

    const float mgx = t[0] / 1024.f;
    const float rgx = 1.f / sqrtf(t[1] / 1024.f - mgx * mgx + LN_EPS);
    const float mgh = t[2] / 1024.f;
    const float rgh = 1.f / sqrtf(t[3] / 1024.f - mgh * mgh + LN_EPS);
    const float mcx = t[4] / 512.f;
    const float rcx = 1.f / sqrtf(t[5] / 512.f - mcx * mcx + LN_EPS);
    const float mch = t[6] / 512.f;
    const float rch = 1.f / sqrtf(t[7] / 512.f - mch * mch + LN_EPS);

    float4 g;
    g.x = sigmoidf_((gx4.x - mgx) * rgx + (gh4.x - mgh) * rgh);
    g.y = sigmoidf_((gx4.y - mgx) * rgx + (gh4.y - mgh) * rgh);
    g.z = sigmoidf_((gx4.z - mgx) * rgx + (gh4.z - mgh) * rgh);
    g.w = sigmoidf_((gx4.w - mgx) * rgx + (gh4.w - mgh) * rgh);
    *(float4*)&s_gates[tid * 4] = g;
    __syncthreads();

    const float2 hp2 = *(const float2*)(hprev + (size_t)b * 512 + tid * 2);
    const float z0 = s_gates[tid * 2 + 0];
    const float z1 = s_gates[tid * 2 + 1];
    const float r0 = s_gates[512 + tid * 2 + 0];
    const float r1 = s_gates[512 + tid * 2 + 1];

    const float hh0 = tanhf((cx2.x - mcx) * rcx + r0 * ((ch2.x - mch) * rch));
    const float hh1 = tanhf((cx2.y - mcx) * rcx + r1 * ((ch2.y - mch) * rch));
    const float hn0 = (1.f - z0) * hp2.x + z0 * hh0;
    const float hn1 = (1.f - z1) * hp2.y + z1 * hh1;

    *(float2*)(hout + (size_t)b * 512 + tid * 2) = make_float2(hn0, hn1);
}

// ---------------------------------------------------------------------------
// Kernel 4: output head. One wave per row. All outputs fp32.
// ---------------------------------------------------------------------------
__global__ __launch_bounds__(256)
void out_kernel(const float* __restrict__ h1,   // B x 512 (fp32, in d_out)
                const float* __restrict__ W,    // 512 x 32
                const float* __restrict__ bias, // 32
                float* __restrict__ out)
{
    __shared__ float s_h[4][512];
    const int wave = threadIdx.x >> 6, lane = threadIdx.x & 63;
    const int b = blockIdx.x * 4 + wave;

    {
        const float4* hp = (const float4*)(h1 + (size_t)b * 512);
        float4* sp = (float4*)&s_h[wave][0];
        sp[lane]      = hp[lane];
        sp[lane + 64] = hp[lane + 64];
    }
    __syncthreads();

    const int v = lane & 31, half = lane >> 5;
    float acc = 0.f;
    {
        const float* wp = W + (size_t)half * 256 * 32 + v;
        const float* hh = &s_h[wave][half * 256];
        for (int k = 0; k < 256; ++k) acc = fmaf(hh[k], wp[(size_t)k * 32], acc);
    }
    acc += __shfl_xor(acc, 32);
    const float logit = acc + bias[v];

    if (half == 0)
        out[(size_t)3 * B_SZ + (size_t)b * VOCAB + v] = logit;

    float mval = logit; int midx = v;
    #pragma unroll
    for (int m = 16; m; m >>= 1) {
        float ov = __shfl_xor(mval, m);
        int   oi = __shfl_xor(midx, m);
        if (ov > mval || (ov == mval && oi < midx)) { mval = ov; midx = oi; }
    }
    float ex = expf(logit - mval);
    float sum = ex;
    #pragma unroll
    for (int m = 16; m; m >>= 1) sum += __shfl_xor(sum, m);
    const float lse  = mval + logf(sum);
    const float logp = logit - lse;
    const float p    = expf(logp);
    float epl = p * logp;
    #pragma unroll
    for (int m = 16; m; m >>= 1) epl += __shfl_xor(epl, m);
    const float entropy = -epl;
    const float tok_logp = __shfl(logp, midx, 32);

    if (lane == 0) {
        out[b]             = (float)midx;
        out[B_SZ + b]      = entropy;
        out[2 * B_SZ + b]  = tok_logp;
    }
}

// ---------------------------------------------------------------------------
extern "C" void kernel_launch(void* const* d_in, const int* in_sizes, int n_in,
                              void* d_out, int out_size, void* d_ws, size_t ws_size,
                              hipStream_t stream)
{
    const float* snd    = (const float*)d_in[0];
    const float* ph     = (const float*)d_in[1];   // 2 x B x H
    const float* co     = (const float*)d_in[2];
    const float* pmsg   = (const float*)d_in[3];
    const float* Wk     = (const float*)d_in[4];
    const float* bk     = (const float*)d_in[5];
    const float* i2hW0  = (const float*)d_in[6];
    const float* i2hb0  = (const float*)d_in[7];
    const float* h2hW0  = (const float*)d_in[8];
    const float* h2hb0  = (const float*)d_in[9];
    const float* hWW0   = (const float*)d_in[10];
    const float* hWb0   = (const float*)d_in[11];
    const float* hUW0   = (const float*)d_in[12];
    const float* hUb0   = (const float*)d_in[13];
    const float* i2hW1  = (const float*)d_in[14];
    const float* i2hb1  = (const float*)d_in[15];
    const float* h2hW1  = (const float*)d_in[16];
    const float* h2hb1  = (const float*)d_in[17];
    const float* hWW1   = (const float*)d_in[18];
    const float* hWb1   = (const float*)d_in[19];
    const float* hUW1   = (const float*)d_in[20];
    const float* hUb1   = (const float*)d_in[21];
    const float* outW   = (const float*)d_in[22];
    const float* outb   = (const float*)d_in[23];

    float* out = (float*)d_out;
    // new_hidden region of d_out (fp32): h0 then h1, each B x 512
    float* h0out = out + (size_t)3 * B_SZ + (size_t)B_SZ * VOCAB;
    float* h1out = h0out + (size_t)B_SZ * H_SZ;

    const float* h0prev = ph;
    const float* h1prev = ph + (size_t)B_SZ * H_SZ;

    // Chunk rows so scratch fits in ws_size (deterministic -> graph-safe).
    // Per-row scratch floats: rnn_in 384 + gx 1024 + gh 1024 + cx 512 + ch 512
    const size_t per_row = 384 + 1024 + 1024 + 512 + 512;   // 3456 floats
    int rows = B_SZ;
    while (rows > 64 && (size_t)rows * per_row * sizeof(float) > ws_size) rows >>= 1;

    float* ws     = (float*)d_ws;
    float* rnn_in = ws;                               // rows*384
    float* gx     = rnn_in + (size_t)rows * 384;      // rows*1024
    float* gh     = gx     + (size_t)rows * 1024;     // rows*1024
    float* cxb    = gh     + (size_t)rows * 1024;     // rows*512
    float* chb    = cxb    + (size_t)rows * 512;      // rows*512

    for (int r0 = 0; r0 < B_SZ; r0 += rows) {
        const float* h0p = h0prev + (size_t)r0 * H_SZ;
        const float* h1p = h1prev + (size_t)r0 * H_SZ;
        float* h0o = h0out + (size_t)r0 * H_SZ;
        float* h1o = h1out + (size_t)r0 * H_SZ;

        attn_kernel<<<rows, 256, 0, stream>>>(co + (size_t)r0 * NCAND * DIN, Wk, bk,
                                              snd + (size_t)r0 * E_SZ,
                                              pmsg + (size_t)r0 * E_SZ, rnn_in);

        // ---- GRU cell 0 ----
        gemm_bias_kernel<<<dim3(1024/64, rows/64), 256, 0, stream>>>(rnn_in, i2hW0, i2hb0, gx, rows, 1024, 384);
        gemm_bias_kernel<<<dim3(1024/64, rows/64), 256, 0, stream>>>(h0p,    h2hW0, h2hb0, gh, rows, 1024, 512);
        gemm_bias_kernel<<<dim3( 512/64, rows/64), 256, 0, stream>>>(rnn_in, hWW0,  hWb0,  cxb, rows,  512, 384);
        gemm_bias_kernel<<<dim3( 512/64, rows/64), 256, 0, stream>>>(h0p,    hUW0,  hUb0,  chb, rows,  512, 512);
        gru_combine_kernel<<<rows, 256, 0, stream>>>(gx, gh, cxb, chb, h0p, h0o);

        // ---- GRU cell 1 ----
        gemm_bias_kernel<<<dim3(1024/64, rows/64), 256, 0, stream>>>(h0o, i2hW1, i2hb1, gx, rows, 1024, 512);
        gemm_bias_kernel<<<dim3(1024/64, rows/64), 256, 0, stream>>>(h1p, h2hW1, h2hb1, gh, rows, 1024, 512);
        gemm_bias_kernel<<<dim3( 512/64, rows/64), 256, 0, stream>>>(h0o, hWW1,  hWb1,  cxb, rows,  512, 512);
        gemm_bias_kernel<<<dim3( 512/64, rows/64), 256, 0, stream>>>(h1p, hUW1,  hUb1,  chb, rows,  512, 512);
        gru_combine_kernel<<<rows, 256, 0, stream>>>(gx, gh, cxb, chb, h1p, h1o);
    }

    // ---- output head ----
    out_kernel<<<B_SZ / 4, 256, 0, stream>>>(h1out, outW, outb, out);
}

// Round 4
// 747.408 us; speedup vs baseline: 1.0256x; 1.0256x over previous
//
#include <hip/hip_runtime.h>
#include <hip/hip_bf16.h>
#include <math.h>

// Problem constants
#define B_SZ   4096
#define NCAND  32
#define DIN    256
#define E_SZ   128
#define H_SZ   512
#define VOCAB  32
#define LN_EPS 1e-5f

static __device__ __forceinline__ float sigmoidf_(float x) {
    return 1.0f / (1.0f + expf(-x));
}

// ---------------------------------------------------------------------------
// Kernel A1: q = A(Mx K) @ Bt(N x K)^T  (no bias). 64x64x16 tiles, 4x4 micro.
// Used for q = snd @ Wk^T (M=rows, N=256, K=128).
// ---------------------------------------------------------------------------
__global__ __launch_bounds__(256)
void gemm_bt64_kernel(const float* __restrict__ A, const float* __restrict__ Bt,
                      float* __restrict__ C, int M, int N, int K, int ldc)
{
    __shared__ float As[16][68];
    __shared__ float Bs[16][68];

    const int tid = threadIdx.x;
    const int bm = blockIdx.y * 64;
    const int bn = blockIdx.x * 64;
    const int tx = tid & 15, ty = tid >> 4;
    const int m0 = ty * 4, n0 = tx * 4;

    const int arow = tid >> 2;        // 0..63
    const int acol = (tid & 3) * 4;   // 0,4,8,12

    float acc[4][4] = {};

    for (int k0 = 0; k0 < K; k0 += 16) {
        float4 a4 = *(const float4*)(A  + (size_t)(bm + arow) * K + (k0 + acol));
        float4 b4 = *(const float4*)(Bt + (size_t)(bn + arow) * K + (k0 + acol));
        As[acol + 0][arow] = a4.x; As[acol + 1][arow] = a4.y;
        As[acol + 2][arow] = a4.z; As[acol + 3][arow] = a4.w;
        Bs[acol + 0][arow] = b4.x; Bs[acol + 1][arow] = b4.y;
        Bs[acol + 2][arow] = b4.z; Bs[acol + 3][arow] = b4.w;
        __syncthreads();
        #pragma unroll
        for (int k = 0; k < 16; ++k) {
            float4 av = *(const float4*)&As[k][m0];
            float4 bv = *(const float4*)&Bs[k][n0];
            float aa[4] = {av.x, av.y, av.z, av.w};
            float bb[4] = {bv.x, bv.y, bv.z, bv.w};
            #pragma unroll
            for (int i = 0; i < 4; ++i)
                #pragma unroll
                for (int j = 0; j < 4; ++j)
                    acc[i][j] = fmaf(aa[i], bb[j], acc[i][j]);
        }
        __syncthreads();
    }

    #pragma unroll
    for (int i = 0; i < 4; ++i) {
        float4 o = make_float4(acc[i][0], acc[i][1], acc[i][2], acc[i][3]);
        *(float4*)(C + (size_t)(bm + m0 + i) * ldc + bn + n0) = o;
    }
}

// ---------------------------------------------------------------------------
// Kernel A2: fused scores/softmax/cbar. Per b: stage co[b] (32x256) in LDS,
// scores[n] = co[b,n]·q[b]; softmax; cbar[d] = sum_n w[n] co[b,n,d].
// Also copies snd/pmsg into rnn_in[b][128:384].
// ---------------------------------------------------------------------------
__global__ __launch_bounds__(256)
void attn_ctx_kernel(const float* __restrict__ co,    // rows x 32 x 256
                     const float* __restrict__ q,     // rows x 256
                     const float* __restrict__ snd,   // rows x 128
                     const float* __restrict__ pmsg,  // rows x 128
                     float* __restrict__ cbar,        // rows x 256
                     float* __restrict__ rnn_in)      // rows x 384
{
    __shared__ float s_co[NCAND][264];   // padded row (264 = 8 mod 32 banks)
    __shared__ float s_q[DIN];
    __shared__ float s_scores[NCAND];
    __shared__ float s_w[NCAND];

    const int b   = blockIdx.x;
    const int tid = threadIdx.x;

    // stage co[b]: 2048 float4
    {
        const float4* cop = (const float4*)(co + (size_t)b * NCAND * DIN);
        #pragma unroll
        for (int i = 0; i < 8; ++i) {
            int idx = tid + i * 256;
            float4 v = cop[idx];
            *(float4*)&s_co[idx >> 6][(idx & 63) * 4] = v;
        }
        if (tid < DIN) s_q[tid] = q[(size_t)b * DIN + tid];
    }
    __syncthreads();

    // scores: n = tid>>3, part = tid&7; each lane covers d = part*4 + qq*32
    {
        const int n = tid >> 3, part = tid & 7;
        float sc = 0.f;
        #pragma unroll
        for (int qq = 0; qq < 8; ++qq) {
            const int d = part * 4 + qq * 32;
            float4 cv = *(const float4*)&s_co[n][d];
            float4 qv = *(const float4*)&s_q[d];
            sc += cv.x * qv.x + cv.y * qv.y + cv.z * qv.z + cv.w * qv.w;
        }
        #pragma unroll
        for (int m = 4; m; m >>= 1) sc += __shfl_xor(sc, m);
        if (part == 0) s_scores[n] = sc;
    }
    __syncthreads();

    if (tid < NCAND) {
        float s  = s_scores[tid];
        float mx = s;
        #pragma unroll
        for (int m = 16; m; m >>= 1) mx = fmaxf(mx, __shfl_xor(mx, m));
        float e = expf(s - mx);
        float sum = e;
        #pragma unroll
        for (int m = 16; m; m >>= 1) sum += __shfl_xor(sum, m);
        s_w[tid] = e / sum;
    }
    __syncthreads();

    // cbar: one d per thread
    {
        const int d = tid;
        float cb = 0.f;
        #pragma unroll
        for (int n = 0; n < NCAND; ++n) cb = fmaf(s_w[n], s_co[n][d], cb);
        cbar[(size_t)b * DIN + d] = cb;
    }
    // concat tail of rnn_in
    if (tid < 128)
        rnn_in[(size_t)b * 384 + 128 + tid] = snd[(size_t)b * E_SZ + tid];
    else
        rnn_in[(size_t)b * 384 + 128 + tid] = pmsg[(size_t)b * E_SZ + (tid - 128)];
}

// ---------------------------------------------------------------------------
// Kernel 2: fp32 GEMM C = A(MxK) @ B(KxN) (+bias), 128x64x16 tiles, 8x4 micro.
// M%128==0, N%64==0, K%16==0. ldc = C row stride.
// ---------------------------------------------------------------------------
template<bool BIAS>
__global__ __launch_bounds__(256)
void gemm_f32_kernel(const float* __restrict__ A, const float* __restrict__ Bm,
                     const float* __restrict__ bias, float* __restrict__ C,
                     int M, int N, int K, int ldc)
{
    __shared__ float As[16][132];   // A^T staged, 128 rows + pad
    __shared__ float Bs[16][68];

    const int tid = threadIdx.x;
    const int bm = blockIdx.y * 128;
    const int bn = blockIdx.x * 64;
    const int tx = tid & 15, ty = tid >> 4;
    const int m0 = ty * 8, n0 = tx * 4;

    const int arow = tid >> 1;           // 0..127
    const int acol = (tid & 1) * 8;      // 0 or 8
    const int brow = tid >> 4;           // 0..15
    const int bcol = (tid & 15) * 4;     // 0..60

    float acc[8][4] = {};

    for (int k0 = 0; k0 < K; k0 += 16) {
        float4 a0 = *(const float4*)(A + (size_t)(bm + arow) * K + (k0 + acol));
        float4 a1 = *(const float4*)(A + (size_t)(bm + arow) * K + (k0 + acol + 4));
        float4 b4 = *(const float4*)(Bm + (size_t)(k0 + brow) * N + (bn + bcol));
        As[acol + 0][arow] = a0.x; As[acol + 1][arow] = a0.y;
        As[acol + 2][arow] = a0.z; As[acol + 3][arow] = a0.w;
        As[acol + 4][arow] = a1.x; As[acol + 5][arow] = a1.y;
        As[acol + 6][arow] = a1.z; As[acol + 7][arow] = a1.w;
        *(float4*)&Bs[brow][bcol] = b4;
        __syncthreads();
        #pragma unroll
        for (int k = 0; k < 16; ++k) {
            float4 av0 = *(const float4*)&As[k][m0];
            float4 av1 = *(const float4*)&As[k][m0 + 4];
            float4 bv  = *(const float4*)&Bs[k][n0];
            float aa[8] = {av0.x, av0.y, av0.z, av0.w, av1.x, av1.y, av1.z, av1.w};
            float bb[4] = {bv.x, bv.y, bv.z, bv.w};
            #pragma unroll
            for (int i = 0; i < 8; ++i)
                #pragma unroll
                for (int j = 0; j < 4; ++j)
                    acc[i][j] = fmaf(aa[i], bb[j], acc[i][j]);
        }
        __syncthreads();
    }

    float4 bv = make_float4(0.f, 0.f, 0.f, 0.f);
    if (BIAS) bv = *(const float4*)(bias + bn + n0);
    #pragma unroll
    for (int i = 0; i < 8; ++i) {
        float4 o;
        o.x = acc[i][0] + bv.x;
        o.y = acc[i][1] + bv.y;
        o.z = acc[i][2] + bv.z;
        o.w = acc[i][3] + bv.w;
        *(float4*)(C + (size_t)(bm + m0 + i) * ldc + bn + n0) = o;
    }
}

// ---------------------------------------------------------------------------
// Kernel 3: per-row LN-GRU combine. Writes h_new (fp32) directly into the
// d_out new_hidden region.
// ---------------------------------------------------------------------------
__global__ __launch_bounds__(256)
void gru_combine_kernel(const float* __restrict__ gx, const float* __restrict__ gh,
                        const float* __restrict__ cx, const float* __restrict__ ch,
                        const float* __restrict__ hprev,
                        float* __restrict__ hout)
{
    const int b    = blockIdx.x;
    const int tid  = threadIdx.x;
    const int lane = tid & 63, wv = tid >> 6;

    __shared__ float s_part[4][8];
    __shared__ float s_gates[1024];

    const float* gxb = gx + (size_t)b * 1024;
    const float* ghb = gh + (size_t)b * 1024;
    const float* cxb = cx + (size_t)b * 512;
    const float* chb = ch + (size_t)b * 512;

    const float4 gx4 = *(const float4*)(gxb + tid * 4);
    const float4 gh4 = *(const float4*)(ghb + tid * 4);
    const float2 cx2 = *(const float2*)(cxb + tid * 2);
    const float2 ch2 = *(const float2*)(chb + tid * 2);

    float v[8];
    v[0] = gx4.x + gx4.y + gx4.z + gx4.w;
    v[1] = gx4.x*gx4.x + gx4.y*gx4.y + gx4.z*gx4.z + gx4.w*gx4.w;
    v[2] = gh4.x + gh4.y + gh4.z + gh4.w;
    v[3] = gh4.x*gh4.x + gh4.y*gh4.y + gh4.z*gh4.z + gh4.w*gh4.w;
    v[4] = cx2.x + cx2.y;
    v[5] = cx2.x*cx2.x + cx2.y*cx2.y;
    v[6] = ch2.x + ch2.y;
    v[7] = ch2.x*ch2.x + ch2.y*ch2.y;

    #pragma unroll
    for (int i = 0; i < 8; ++i)
        #pragma unroll
        for (int m = 32; m; m >>= 1) v[i] += __shfl_xor(v[i], m);

    if (lane == 0) {
        #pragma unroll
        for (int i = 0; i < 8; ++i) s_part[wv][i] = v[i];
    }
    __syncthreads();

    float t[8];
    #pragma unroll
    for (int i = 0; i < 8; ++i)
        t[i] = s_part[0][i] + s_part[1][i] + s_part[2][i] + s_part[3][i];

    const float mgx = t[0] / 1024.f;
    const float rgx = 1.f / sqrtf(t[1] / 1024.f - mgx * mgx + LN_EPS);
    const float mgh = t[2] / 1024.f;
    const float rgh = 1.f / sqrtf(t[3] / 1024.f - mgh * mgh + LN_EPS);
    const float mcx = t[4] / 512.f;
    const float rcx = 1.f / sqrtf(t[5] / 512.f - mcx * mcx + LN_EPS);
    const float mch = t[6] / 512.f;
    const float rch = 1.f / sqrtf(t[7] / 512.f - mch * mch + LN_EPS);

    float4 g;
    g.x = sigmoidf_((gx4.x - mgx) * rgx + (gh4.x - mgh) * rgh);
    g.y = sigmoidf_((gx4.y - mgx) * rgx + (gh4.y - mgh) * rgh);
    g.z = sigmoidf_((gx4.z - mgx) * rgx + (gh4.z - mgh) * rgh);
    g.w = sigmoidf_((gx4.w - mgx) * rgx + (gh4.w - mgh) * rgh);
    *(float4*)&s_gates[tid * 4] = g;
    __syncthreads();

    const float2 hp2 = *(const float2*)(hprev + (size_t)b * 512 + tid * 2);
    const float z0 = s_gates[tid * 2 + 0];
    const float z1 = s_gates[tid * 2 + 1];
    const float r0 = s_gates[512 + tid * 2 + 0];
    const float r1 = s_gates[512 + tid * 2 + 1];

    const float hh0 = tanhf((cx2.x - mcx) * rcx + r0 * ((ch2.x - mch) * rch));
    const float hh1 = tanhf((cx2.y - mcx) * rcx + r1 * ((ch2.y - mch) * rch));
    const float hn0 = (1.f - z0) * hp2.x + z0 * hh0;
    const float hn1 = (1.f - z1) * hp2.y + z1 * hh1;

    *(float2*)(hout + (size_t)b * 512 + tid * 2) = make_float2(hn0, hn1);
}

// ---------------------------------------------------------------------------
// Kernel 4: output head. One wave per row. All outputs fp32.
// ---------------------------------------------------------------------------
__global__ __launch_bounds__(256)
void out_kernel(const float* __restrict__ h1,   // B x 512 (fp32, in d_out)
                const float* __restrict__ W,    // 512 x 32
                const float* __restrict__ bias, // 32
                float* __restrict__ out)
{
    __shared__ float s_h[4][512];
    const int wave = threadIdx.x >> 6, lane = threadIdx.x & 63;
    const int b = blockIdx.x * 4 + wave;

    {
        const float4* hp = (const float4*)(h1 + (size_t)b * 512);
        float4* sp = (float4*)&s_h[wave][0];
        sp[lane]      = hp[lane];
        sp[lane + 64] = hp[lane + 64];
    }
    __syncthreads();

    const int v = lane & 31, half = lane >> 5;
    float acc = 0.f;
    {
        const float* wp = W + (size_t)half * 256 * 32 + v;
        const float* hh = &s_h[wave][half * 256];
        for (int k = 0; k < 256; ++k) acc = fmaf(hh[k], wp[(size_t)k * 32], acc);
    }
    acc += __shfl_xor(acc, 32);
    const float logit = acc + bias[v];

    if (half == 0)
        out[(size_t)3 * B_SZ + (size_t)b * VOCAB + v] = logit;

    float mval = logit; int midx = v;
    #pragma unroll
    for (int m = 16; m; m >>= 1) {
        float ov = __shfl_xor(mval, m);
        int   oi = __shfl_xor(midx, m);
        if (ov > mval || (ov == mval && oi < midx)) { mval = ov; midx = oi; }
    }
    float ex = expf(logit - mval);
    float sum = ex;
    #pragma unroll
    for (int m = 16; m; m >>= 1) sum += __shfl_xor(sum, m);
    const float lse  = mval + logf(sum);
    const float logp = logit - lse;
    const float p    = expf(logp);
    float epl = p * logp;
    #pragma unroll
    for (int m = 16; m; m >>= 1) epl += __shfl_xor(epl, m);
    const float entropy = -epl;
    const float tok_logp = __shfl(logp, midx, 32);

    if (lane == 0) {
        out[b]             = (float)midx;
        out[B_SZ + b]      = entropy;
        out[2 * B_SZ + b]  = tok_logp;
    }
}

// ---------------------------------------------------------------------------
extern "C" void kernel_launch(void* const* d_in, const int* in_sizes, int n_in,
                              void* d_out, int out_size, void* d_ws, size_t ws_size,
                              hipStream_t stream)
{
    const float* snd    = (const float*)d_in[0];
    const float* ph     = (const float*)d_in[1];   // 2 x B x H
    const float* co     = (const float*)d_in[2];
    const float* pmsg   = (const float*)d_in[3];
    const float* Wk     = (const float*)d_in[4];
    const float* bk     = (const float*)d_in[5];
    const float* i2hW0  = (const float*)d_in[6];
    const float* i2hb0  = (const float*)d_in[7];
    const float* h2hW0  = (const float*)d_in[8];
    const float* h2hb0  = (const float*)d_in[9];
    const float* hWW0   = (const float*)d_in[10];
    const float* hWb0   = (const float*)d_in[11];
    const float* hUW0   = (const float*)d_in[12];
    const float* hUb0   = (const float*)d_in[13];
    const float* i2hW1  = (const float*)d_in[14];
    const float* i2hb1  = (const float*)d_in[15];
    const float* h2hW1  = (const float*)d_in[16];
    const float* h2hb1  = (const float*)d_in[17];
    const float* hWW1   = (const float*)d_in[18];
    const float* hWb1   = (const float*)d_in[19];
    const float* hUW1   = (const float*)d_in[20];
    const float* hUb1   = (const float*)d_in[21];
    const float* outW   = (const float*)d_in[22];
    const float* outb   = (const float*)d_in[23];

    float* out = (float*)d_out;
    float* h0out = out + (size_t)3 * B_SZ + (size_t)B_SZ * VOCAB;
    float* h1out = h0out + (size_t)B_SZ * H_SZ;

    const float* h0prev = ph;
    const float* h1prev = ph + (size_t)B_SZ * H_SZ;

    // Chunk rows so scratch fits in ws_size (deterministic -> graph-safe).
    // Per-row floats: q 256 + cbar 256 + rnn_in 384 + gx 1024 + gh 1024 + cx 512 + ch 512
    const size_t per_row = 256 + 256 + 384 + 1024 + 1024 + 512 + 512;  // 3968
    int rows = B_SZ;
    while (rows > 128 && (size_t)rows * per_row * sizeof(float) > ws_size) rows >>= 1;

    float* ws     = (float*)d_ws;
    float* qbuf   = ws;                               // rows*256
    float* cbar   = qbuf   + (size_t)rows * 256;      // rows*256
    float* rnn_in = cbar   + (size_t)rows * 256;      // rows*384
    float* gx     = rnn_in + (size_t)rows * 384;      // rows*1024
    float* gh     = gx     + (size_t)rows * 1024;     // rows*1024
    float* cxb    = gh     + (size_t)rows * 1024;     // rows*512
    float* chb    = cxb    + (size_t)rows * 512;      // rows*512

    for (int r0 = 0; r0 < B_SZ; r0 += rows) {
        const float* h0p = h0prev + (size_t)r0 * H_SZ;
        const float* h1p = h1prev + (size_t)r0 * H_SZ;
        float* h0o = h0out + (size_t)r0 * H_SZ;
        float* h1o = h1out + (size_t)r0 * H_SZ;
        const float* sndc  = snd  + (size_t)r0 * E_SZ;
        const float* pmsgc = pmsg + (size_t)r0 * E_SZ;

        // ---- attention (refactored) ----
        // q = snd @ Wk^T  (rows x 256, K=128)
        gemm_bt64_kernel<<<dim3(256/64, rows/64), 256, 0, stream>>>(
            sndc, Wk, qbuf, rows, 256, 128, 256);
        // scores/softmax/cbar + concat tail
        attn_ctx_kernel<<<rows, 256, 0, stream>>>(
            co + (size_t)r0 * NCAND * DIN, qbuf, sndc, pmsgc, cbar, rnn_in);
        // context = cbar @ Wk + bk -> rnn_in[:, 0:128] (ldc=384)
        gemm_f32_kernel<true><<<dim3(128/64, rows/128), 256, 0, stream>>>(
            cbar, Wk, bk, rnn_in, rows, 128, 256, 384);

        // ---- GRU cell 0 ----
        gemm_f32_kernel<true><<<dim3(1024/64, rows/128), 256, 0, stream>>>(rnn_in, i2hW0, i2hb0, gx, rows, 1024, 384, 1024);
        gemm_f32_kernel<true><<<dim3(1024/64, rows/128), 256, 0, stream>>>(h0p,    h2hW0, h2hb0, gh, rows, 1024, 512, 1024);
        gemm_f32_kernel<true><<<dim3( 512/64, rows/128), 256, 0, stream>>>(rnn_in, hWW0,  hWb0,  cxb, rows,  512, 384, 512);
        gemm_f32_kernel<true><<<dim3( 512/64, rows/128), 256, 0, stream>>>(h0p,    hUW0,  hUb0,  chb, rows,  512, 512, 512);
        gru_combine_kernel<<<rows, 256, 0, stream>>>(gx, gh, cxb, chb, h0p, h0o);

        // ---- GRU cell 1 ----
        gemm_f32_kernel<true><<<dim3(1024/64, rows/128), 256, 0, stream>>>(h0o, i2hW1, i2hb1, gx, rows, 1024, 512, 1024);
        gemm_f32_kernel<true><<<dim3(1024/64, rows/128), 256, 0, stream>>>(h1p, h2hW1, h2hb1, gh, rows, 1024, 512, 1024);
        gemm_f32_kernel<true><<<dim3( 512/64, rows/128), 256, 0, stream>>>(h0o, hWW1,  hWb1,  cxb, rows,  512, 512, 512);
        gemm_f32_kernel<true><<<dim3( 512/64, rows/128), 256, 0, stream>>>(h1p, hUW1,  hUb1,  chb, rows,  512, 512, 512);
        gru_combine_kernel<<<rows, 256, 0, stream>>>(gx, gh, cxb, chb, h1p, h1o);
    }

    // ---- output head ----
    out_kernel<<<B_SZ / 4, 256, 0, stream>>>(h1out, outW, outb, out);
}

// Round 5
// 479.878 us; speedup vs baseline: 1.5974x; 1.5575x over previous
//
#include <hip/hip_runtime.h>
#include <hip/hip_bf16.h>
#include <math.h>

// Problem constants
#define B_SZ   4096
#define NCAND  32
#define DIN    256
#define E_SZ   128
#define H_SZ   512
#define VOCAB  32
#define LN_EPS 1e-5f

typedef unsigned short u16;
typedef unsigned int   u32;
typedef __attribute__((ext_vector_type(8))) short  short8;   // 8 bf16 (4 VGPR)
typedef __attribute__((ext_vector_type(4))) float  floatx4;  // MFMA acc

static __device__ __forceinline__ float sigmoidf_(float x) {
    return 1.0f / (1.0f + expf(-x));
}
// fp32 -> bf16 (RNE), finite inputs
static __device__ __forceinline__ u16 f2bf(float x) {
    u32 u = __float_as_uint(x);
    return (u16)((u + 0x7FFFu + ((u >> 16) & 1u)) >> 16);
}
static __device__ __forceinline__ float bfbits2f(u16 h) {
    return __uint_as_float(((u32)h) << 16);
}

// ---------------------------------------------------------------------------
// Weight prep: Wt_hi/Wt_lo[n][k] (bf16, N-major) from [W1 | W2] (K x N1, K x N2)
// ---------------------------------------------------------------------------
__global__ __launch_bounds__(256)
void transpose_split_w(const float* __restrict__ W1, const float* __restrict__ W2,
                       int N1, int N2, int K,
                       u16* __restrict__ Wt_hi, u16* __restrict__ Wt_lo)
{
    __shared__ float t[64][68];
    const int n0 = blockIdx.x * 64, k0 = blockIdx.y * 64;
    const int tid = threadIdx.x;

    {
        const int kl = tid >> 4, nl4 = (tid & 15) * 4;
        const int ng = n0 + nl4;
        const float* src; int col, ld;
        if (ng < N1) { src = W1; col = ng;      ld = N1; }
        else         { src = W2; col = ng - N1; ld = N2; }
        #pragma unroll
        for (int p = 0; p < 4; ++p) {
            float4 v = *(const float4*)(src + (size_t)(k0 + kl + p * 16) * ld + col);
            *(float4*)&t[kl + p * 16][nl4] = v;
        }
    }
    __syncthreads();

    const int nl = tid >> 2, kc = tid & 3;
    union { u16 us[16]; uint4 v[2]; } hb, lb;
    #pragma unroll
    for (int j = 0; j < 16; ++j) {
        float x = t[kc * 16 + j][nl];
        u16 h = f2bf(x);
        float r = x - bfbits2f(h);
        hb.us[j] = h;
        lb.us[j] = f2bf(r);
    }
    const size_t off = (size_t)(n0 + nl) * K + k0 + kc * 16;
    *(uint4*)(Wt_hi + off)     = hb.v[0];
    *(uint4*)(Wt_hi + off + 8) = hb.v[1];
    *(uint4*)(Wt_lo + off)     = lb.v[0];
    *(uint4*)(Wt_lo + off + 8) = lb.v[1];
}

__global__ __launch_bounds__(256)
void bias_cat_kernel(const float* __restrict__ b1, const float* __restrict__ b2,
                     int N1, int Ntot, float* __restrict__ out)
{
    int i = blockIdx.x * 256 + threadIdx.x;
    if (i < Ntot) out[i] = (i < N1) ? b1[i] : b2[i - N1];
}

// Activation split: fp32 (len = 4*n4) -> hi/lo bf16 (same layout)
__global__ __launch_bounds__(256)
void split_act_kernel(const float* __restrict__ src,
                      u16* __restrict__ hi, u16* __restrict__ lo, int n4)
{
    int i = blockIdx.x * 256 + threadIdx.x;
    if (i >= n4) return;
    float4 v = ((const float4*)src)[i];
    u16 h0 = f2bf(v.x), h1 = f2bf(v.y), h2 = f2bf(v.z), h3 = f2bf(v.w);
    u16 l0 = f2bf(v.x - bfbits2f(h0));
    u16 l1 = f2bf(v.y - bfbits2f(h1));
    u16 l2 = f2bf(v.z - bfbits2f(h2));
    u16 l3 = f2bf(v.w - bfbits2f(h3));
    uint2 hv, lv;
    hv.x = (u32)h0 | ((u32)h1 << 16); hv.y = (u32)h2 | ((u32)h3 << 16);
    lv.x = (u32)l0 | ((u32)l1 << 16); lv.y = (u32)l2 | ((u32)l3 << 16);
    ((uint2*)hi)[i] = hv;
    ((uint2*)lo)[i] = lv;
}

// ---------------------------------------------------------------------------
// Split-bf16 MFMA GEMM: C(MxN) = A(MxK) @ W(KxN) + bias, where
// A is given as Ah/Al (bf16 hi/lo, row-major MxK) and W as Wth/Wtl (bf16,
// N-major: Wt[n][k]). acc += Ah*Wh + Ah*Wl + Al*Wh (fp32 MFMA accum).
// 128x128 block tile, 4 waves, each wave 64x64 = 4x4 MFMA 16x16x32 tiles.
// ---------------------------------------------------------------------------
__global__ __launch_bounds__(256)
void mfma_gemm_kernel(const u16* __restrict__ Ah, const u16* __restrict__ Al,
                      const u16* __restrict__ Wth, const u16* __restrict__ Wtl,
                      const float* __restrict__ bias, float* __restrict__ C,
                      int M, int N, int K)
{
    // LDS: 128 rows x 32 k (bf16), row padded to 40 elems (80 B) for 2-way-max
    // bank conflicts on 16B frag reads. 4 x 10 KB = 40 KB.
    __shared__ u16 sAh[128 * 40];
    __shared__ u16 sAl[128 * 40];
    __shared__ u16 sWh[128 * 40];
    __shared__ u16 sWl[128 * 40];

    const int tid  = threadIdx.x;
    const int lane = tid & 63;
    const int wave = tid >> 6;
    const int wm = (wave >> 1) * 64;     // wave m-offset in tile
    const int wn = (wave & 1) * 64;      // wave n-offset in tile
    const int r16 = lane & 15;
    const int q8  = (lane >> 4) * 8;     // k-offset within 32-k window

    const int m_base = blockIdx.y * 128;
    const int n_base = blockIdx.x * 128;

    // staging coords: 512 16B-chunks per matrix, 2 per thread
    const int row0 = tid >> 2,         col0 = (tid & 3) * 8;
    const int row1 = (tid + 256) >> 2, col1 = ((tid + 256) & 3) * 8;

    floatx4 acc[4][4] = {};

    for (int k0 = 0; k0 < K; k0 += 32) {
        {
            const size_t gA0 = (size_t)(m_base + row0) * K + k0 + col0;
            const size_t gA1 = (size_t)(m_base + row1) * K + k0 + col1;
            const size_t gW0 = (size_t)(n_base + row0) * K + k0 + col0;
            const size_t gW1 = (size_t)(n_base + row1) * K + k0 + col1;
            *(uint4*)&sAh[row0 * 40 + col0] = *(const uint4*)(Ah + gA0);
            *(uint4*)&sAh[row1 * 40 + col1] = *(const uint4*)(Ah + gA1);
            *(uint4*)&sAl[row0 * 40 + col0] = *(const uint4*)(Al + gA0);
            *(uint4*)&sAl[row1 * 40 + col1] = *(const uint4*)(Al + gA1);
            *(uint4*)&sWh[row0 * 40 + col0] = *(const uint4*)(Wth + gW0);
            *(uint4*)&sWh[row1 * 40 + col1] = *(const uint4*)(Wth + gW1);
            *(uint4*)&sWl[row0 * 40 + col0] = *(const uint4*)(Wtl + gW0);
            *(uint4*)&sWl[row1 * 40 + col1] = *(const uint4*)(Wtl + gW1);
        }
        __syncthreads();

        short8 ah[4], al[4], bh[4], bl[4];
        #pragma unroll
        for (int i = 0; i < 4; ++i) {
            const int ar = (wm + i * 16 + r16) * 40 + q8;
            ah[i] = *(const short8*)&sAh[ar];
            al[i] = *(const short8*)&sAl[ar];
            const int br = (wn + i * 16 + r16) * 40 + q8;
            bh[i] = *(const short8*)&sWh[br];
            bl[i] = *(const short8*)&sWl[br];
        }
        #pragma unroll
        for (int i = 0; i < 4; ++i)
            #pragma unroll
            for (int j = 0; j < 4; ++j) {
                acc[i][j] = __builtin_amdgcn_mfma_f32_16x16x32_bf16(ah[i], bh[j], acc[i][j], 0, 0, 0);
                acc[i][j] = __builtin_amdgcn_mfma_f32_16x16x32_bf16(ah[i], bl[j], acc[i][j], 0, 0, 0);
                acc[i][j] = __builtin_amdgcn_mfma_f32_16x16x32_bf16(al[i], bh[j], acc[i][j], 0, 0, 0);
            }
        __syncthreads();
    }

    // epilogue: C/D mapping col=lane&15, row=(lane>>4)*4+reg
    const int quad = lane >> 4;
    #pragma unroll
    for (int j = 0; j < 4; ++j) {
        const int n = n_base + wn + j * 16 + r16;
        const float bv = bias[n];
        #pragma unroll
        for (int i = 0; i < 4; ++i) {
            #pragma unroll
            for (int r = 0; r < 4; ++r) {
                const int m = m_base + wm + i * 16 + quad * 4 + r;
                C[(size_t)m * N + n] = acc[i][j][r] + bv;
            }
        }
    }
}

// ---------------------------------------------------------------------------
// q = A(MxK) @ Bt(NxK)^T. 64x64x16 tiles, 4x4 micro. (q = snd @ Wk^T)
// ---------------------------------------------------------------------------
__global__ __launch_bounds__(256)
void gemm_bt64_kernel(const float* __restrict__ A, const float* __restrict__ Bt,
                      float* __restrict__ C, int M, int N, int K, int ldc)
{
    __shared__ float As[16][68];
    __shared__ float Bs[16][68];

    const int tid = threadIdx.x;
    const int bm = blockIdx.y * 64;
    const int bn = blockIdx.x * 64;
    const int tx = tid & 15, ty = tid >> 4;
    const int m0 = ty * 4, n0 = tx * 4;
    const int arow = tid >> 2, acol = (tid & 3) * 4;

    float acc[4][4] = {};

    for (int k0 = 0; k0 < K; k0 += 16) {
        float4 a4 = *(const float4*)(A  + (size_t)(bm + arow) * K + (k0 + acol));
        float4 b4 = *(const float4*)(Bt + (size_t)(bn + arow) * K + (k0 + acol));
        As[acol + 0][arow] = a4.x; As[acol + 1][arow] = a4.y;
        As[acol + 2][arow] = a4.z; As[acol + 3][arow] = a4.w;
        Bs[acol + 0][arow] = b4.x; Bs[acol + 1][arow] = b4.y;
        Bs[acol + 2][arow] = b4.z; Bs[acol + 3][arow] = b4.w;
        __syncthreads();
        #pragma unroll
        for (int k = 0; k < 16; ++k) {
            float4 av = *(const float4*)&As[k][m0];
            float4 bv = *(const float4*)&Bs[k][n0];
            float aa[4] = {av.x, av.y, av.z, av.w};
            float bb[4] = {bv.x, bv.y, bv.z, bv.w};
            #pragma unroll
            for (int i = 0; i < 4; ++i)
                #pragma unroll
                for (int j = 0; j < 4; ++j)
                    acc[i][j] = fmaf(aa[i], bb[j], acc[i][j]);
        }
        __syncthreads();
    }

    #pragma unroll
    for (int i = 0; i < 4; ++i)
        *(float4*)(C + (size_t)(bm + m0 + i) * ldc + bn + n0) =
            make_float4(acc[i][0], acc[i][1], acc[i][2], acc[i][3]);
}

// ---------------------------------------------------------------------------
// fused scores/softmax/cbar + rnn_in tail copy
// ---------------------------------------------------------------------------
__global__ __launch_bounds__(256)
void attn_ctx_kernel(const float* __restrict__ co, const float* __restrict__ q,
                     const float* __restrict__ snd, const float* __restrict__ pmsg,
                     float* __restrict__ cbar, float* __restrict__ rnn_in)
{
    __shared__ float s_co[NCAND][264];
    __shared__ float s_q[DIN];
    __shared__ float s_scores[NCAND];
    __shared__ float s_w[NCAND];

    const int b   = blockIdx.x;
    const int tid = threadIdx.x;

    {
        const float4* cop = (const float4*)(co + (size_t)b * NCAND * DIN);
        #pragma unroll
        for (int i = 0; i < 8; ++i) {
            int idx = tid + i * 256;
            float4 v = cop[idx];
            *(float4*)&s_co[idx >> 6][(idx & 63) * 4] = v;
        }
        if (tid < DIN) s_q[tid] = q[(size_t)b * DIN + tid];
    }
    __syncthreads();

    {
        const int n = tid >> 3, part = tid & 7;
        float sc = 0.f;
        #pragma unroll
        for (int qq = 0; qq < 8; ++qq) {
            const int d = part * 4 + qq * 32;
            float4 cv = *(const float4*)&s_co[n][d];
            float4 qv = *(const float4*)&s_q[d];
            sc += cv.x * qv.x + cv.y * qv.y + cv.z * qv.z + cv.w * qv.w;
        }
        #pragma unroll
        for (int m = 4; m; m >>= 1) sc += __shfl_xor(sc, m);
        if (part == 0) s_scores[n] = sc;
    }
    __syncthreads();

    if (tid < NCAND) {
        float s  = s_scores[tid];
        float mx = s;
        #pragma unroll
        for (int m = 16; m; m >>= 1) mx = fmaxf(mx, __shfl_xor(mx, m));
        float e = expf(s - mx);
        float sum = e;
        #pragma unroll
        for (int m = 16; m; m >>= 1) sum += __shfl_xor(sum, m);
        s_w[tid] = e / sum;
    }
    __syncthreads();

    {
        float cb = 0.f;
        #pragma unroll
        for (int n = 0; n < NCAND; ++n) cb = fmaf(s_w[n], s_co[n][tid], cb);
        cbar[(size_t)b * DIN + tid] = cb;
    }
    if (tid < 128)
        rnn_in[(size_t)b * 384 + 128 + tid] = snd[(size_t)b * E_SZ + tid];
    else
        rnn_in[(size_t)b * 384 + 128 + tid] = pmsg[(size_t)b * E_SZ + (tid - 128)];
}

// ---------------------------------------------------------------------------
// context = cbar @ Wk + bk -> rnn_in[:,0:128] (fp32 vector GEMM, 128x64 tile)
// ---------------------------------------------------------------------------
__global__ __launch_bounds__(256)
void gemm_ctx_kernel(const float* __restrict__ A, const float* __restrict__ Bm,
                     const float* __restrict__ bias, float* __restrict__ C,
                     int M, int N, int K, int ldc)
{
    __shared__ float As[16][132];
    __shared__ float Bs[16][68];

    const int tid = threadIdx.x;
    const int bm = blockIdx.y * 128;
    const int bn = blockIdx.x * 64;
    const int tx = tid & 15, ty = tid >> 4;
    const int m0 = ty * 8, n0 = tx * 4;
    const int arow = tid >> 1, acol = (tid & 1) * 8;
    const int brow = tid >> 4, bcol = (tid & 15) * 4;

    float acc[8][4] = {};

    for (int k0 = 0; k0 < K; k0 += 16) {
        float4 a0 = *(const float4*)(A + (size_t)(bm + arow) * K + (k0 + acol));
        float4 a1 = *(const float4*)(A + (size_t)(bm + arow) * K + (k0 + acol + 4));
        float4 b4 = *(const float4*)(Bm + (size_t)(k0 + brow) * N + (bn + bcol));
        As[acol + 0][arow] = a0.x; As[acol + 1][arow] = a0.y;
        As[acol + 2][arow] = a0.z; As[acol + 3][arow] = a0.w;
        As[acol + 4][arow] = a1.x; As[acol + 5][arow] = a1.y;
        As[acol + 6][arow] = a1.z; As[acol + 7][arow] = a1.w;
        *(float4*)&Bs[brow][bcol] = b4;
        __syncthreads();
        #pragma unroll
        for (int k = 0; k < 16; ++k) {
            float4 av0 = *(const float4*)&As[k][m0];
            float4 av1 = *(const float4*)&As[k][m0 + 4];
            float4 bv  = *(const float4*)&Bs[k][n0];
            float aa[8] = {av0.x, av0.y, av0.z, av0.w, av1.x, av1.y, av1.z, av1.w};
            float bb[4] = {bv.x, bv.y, bv.z, bv.w};
            #pragma unroll
            for (int i = 0; i < 8; ++i)
                #pragma unroll
                for (int j = 0; j < 4; ++j)
                    acc[i][j] = fmaf(aa[i], bb[j], acc[i][j]);
        }
        __syncthreads();
    }

    const float4 bv = *(const float4*)(bias + bn + n0);
    #pragma unroll
    for (int i = 0; i < 8; ++i) {
        float4 o;
        o.x = acc[i][0] + bv.x; o.y = acc[i][1] + bv.y;
        o.z = acc[i][2] + bv.z; o.w = acc[i][3] + bv.w;
        *(float4*)(C + (size_t)(bm + m0 + i) * ldc + bn + n0) = o;
    }
}

// ---------------------------------------------------------------------------
// LN-GRU combine, concat layout: gxc/ghc rows of 1536 = [gates 1024 | cand 512]
// ---------------------------------------------------------------------------
__global__ __launch_bounds__(256)
void gru_combine_kernel(const float* __restrict__ gxc, const float* __restrict__ ghc,
                        const float* __restrict__ hprev, float* __restrict__ hout)
{
    const int b    = blockIdx.x;
    const int tid  = threadIdx.x;
    const int lane = tid & 63, wv = tid >> 6;

    __shared__ float s_part[4][8];
    __shared__ float s_gates[1024];

    const float* gxb = gxc + (size_t)b * 1536;
    const float* ghb = ghc + (size_t)b * 1536;

    const float4 gx4 = *(const float4*)(gxb + tid * 4);
    const float4 gh4 = *(const float4*)(ghb + tid * 4);
    const float2 cx2 = *(const float2*)(gxb + 1024 + tid * 2);
    const float2 ch2 = *(const float2*)(ghb + 1024 + tid * 2);

    float v[8];
    v[0] = gx4.x + gx4.y + gx4.z + gx4.w;
    v[1] = gx4.x*gx4.x + gx4.y*gx4.y + gx4.z*gx4.z + gx4.w*gx4.w;
    v[2] = gh4.x + gh4.y + gh4.z + gh4.w;
    v[3] = gh4.x*gh4.x + gh4.y*gh4.y + gh4.z*gh4.z + gh4.w*gh4.w;
    v[4] = cx2.x + cx2.y;
    v[5] = cx2.x*cx2.x + cx2.y*cx2.y;
    v[6] = ch2.x + ch2.y;
    v[7] = ch2.x*ch2.x + ch2.y*ch2.y;

    #pragma unroll
    for (int i = 0; i < 8; ++i)
        #pragma unroll
        for (int m = 32; m; m >>= 1) v[i] += __shfl_xor(v[i], m);

    if (lane == 0) {
        #pragma unroll
        for (int i = 0; i < 8; ++i) s_part[wv][i] = v[i];
    }
    __syncthreads();

    float t[8];
    #pragma unroll
    for (int i = 0; i < 8; ++i)
        t[i] = s_part[0][i] + s_part[1][i] + s_part[2][i] + s_part[3][i];

    const float mgx = t[0] / 1024.f;
    const float rgx = 1.f / sqrtf(t[1] / 1024.f - mgx * mgx + LN_EPS);
    const float mgh = t[2] / 1024.f;
    const float rgh = 1.f / sqrtf(t[3] / 1024.f - mgh * mgh + LN_EPS);
    const float mcx = t[4] / 512.f;
    const float rcx = 1.f / sqrtf(t[5] / 512.f - mcx * mcx + LN_EPS);
    const float mch = t[6] / 512.f;
    const float rch = 1.f / sqrtf(t[7] / 512.f - mch * mch + LN_EPS);

    float4 g;
    g.x = sigmoidf_((gx4.x - mgx) * rgx + (gh4.x - mgh) * rgh);
    g.y = sigmoidf_((gx4.y - mgx) * rgx + (gh4.y - mgh) * rgh);
    g.z = sigmoidf_((gx4.z - mgx) * rgx + (gh4.z - mgh) * rgh);
    g.w = sigmoidf_((gx4.w - mgx) * rgx + (gh4.w - mgh) * rgh);
    *(float4*)&s_gates[tid * 4] = g;
    __syncthreads();

    const float2 hp2 = *(const float2*)(hprev + (size_t)b * 512 + tid * 2);
    const float z0 = s_gates[tid * 2 + 0];
    const float z1 = s_gates[tid * 2 + 1];
    const float r0 = s_gates[512 + tid * 2 + 0];
    const float r1 = s_gates[512 + tid * 2 + 1];

    const float hh0 = tanhf((cx2.x - mcx) * rcx + r0 * ((ch2.x - mch) * rch));
    const float hh1 = tanhf((cx2.y - mcx) * rcx + r1 * ((ch2.y - mch) * rch));
    const float hn0 = (1.f - z0) * hp2.x + z0 * hh0;
    const float hn1 = (1.f - z1) * hp2.y + z1 * hh1;

    *(float2*)(hout + (size_t)b * 512 + tid * 2) = make_float2(hn0, hn1);
}

// ---------------------------------------------------------------------------
// output head (unchanged)
// ---------------------------------------------------------------------------
__global__ __launch_bounds__(256)
void out_kernel(const float* __restrict__ h1, const float* __restrict__ W,
                const float* __restrict__ bias, float* __restrict__ out)
{
    __shared__ float s_h[4][512];
    const int wave = threadIdx.x >> 6, lane = threadIdx.x & 63;
    const int b = blockIdx.x * 4 + wave;

    {
        const float4* hp = (const float4*)(h1 + (size_t)b * 512);
        float4* sp = (float4*)&s_h[wave][0];
        sp[lane]      = hp[lane];
        sp[lane + 64] = hp[lane + 64];
    }
    __syncthreads();

    const int v = lane & 31, half = lane >> 5;
    float acc = 0.f;
    {
        const float* wp = W + (size_t)half * 256 * 32 + v;
        const float* hh = &s_h[wave][half * 256];
        for (int k = 0; k < 256; ++k) acc = fmaf(hh[k], wp[(size_t)k * 32], acc);
    }
    acc += __shfl_xor(acc, 32);
    const float logit = acc + bias[v];

    if (half == 0)
        out[(size_t)3 * B_SZ + (size_t)b * VOCAB + v] = logit;

    float mval = logit; int midx = v;
    #pragma unroll
    for (int m = 16; m; m >>= 1) {
        float ov = __shfl_xor(mval, m);
        int   oi = __shfl_xor(midx, m);
        if (ov > mval || (ov == mval && oi < midx)) { mval = ov; midx = oi; }
    }
    float ex = expf(logit - mval);
    float sum = ex;
    #pragma unroll
    for (int m = 16; m; m >>= 1) sum += __shfl_xor(sum, m);
    const float lse  = mval + logf(sum);
    const float logp = logit - lse;
    const float p    = expf(logp);
    float epl = p * logp;
    #pragma unroll
    for (int m = 16; m; m >>= 1) epl += __shfl_xor(epl, m);
    const float entropy = -epl;
    const float tok_logp = __shfl(logp, midx, 32);

    if (lane == 0) {
        out[b]             = (float)midx;
        out[B_SZ + b]      = entropy;
        out[2 * B_SZ + b]  = tok_logp;
    }
}

// ---------------------------------------------------------------------------
extern "C" void kernel_launch(void* const* d_in, const int* in_sizes, int n_in,
                              void* d_out, int out_size, void* d_ws, size_t ws_size,
                              hipStream_t stream)
{
    const float* snd    = (const float*)d_in[0];
    const float* ph     = (const float*)d_in[1];   // 2 x B x H
    const float* co     = (const float*)d_in[2];
    const float* pmsg   = (const float*)d_in[3];
    const float* Wk     = (const float*)d_in[4];
    const float* bk     = (const float*)d_in[5];
    const float* i2hW0  = (const float*)d_in[6];
    const float* i2hb0  = (const float*)d_in[7];
    const float* h2hW0  = (const float*)d_in[8];
    const float* h2hb0  = (const float*)d_in[9];
    const float* hWW0   = (const float*)d_in[10];
    const float* hWb0   = (const float*)d_in[11];
    const float* hUW0   = (const float*)d_in[12];
    const float* hUb0   = (const float*)d_in[13];
    const float* i2hW1  = (const float*)d_in[14];
    const float* i2hb1  = (const float*)d_in[15];
    const float* h2hW1  = (const float*)d_in[16];
    const float* h2hb1  = (const float*)d_in[17];
    const float* hWW1   = (const float*)d_in[18];
    const float* hWb1   = (const float*)d_in[19];
    const float* hUW1   = (const float*)d_in[20];
    const float* hUb1   = (const float*)d_in[21];
    const float* outW   = (const float*)d_in[22];
    const float* outb   = (const float*)d_in[23];

    float* out = (float*)d_out;
    float* h0out = out + (size_t)3 * B_SZ + (size_t)B_SZ * VOCAB;
    float* h1out = h0out + (size_t)B_SZ * H_SZ;

    const float* h0prev = ph;
    const float* h1prev = ph + (size_t)B_SZ * H_SZ;

    // ---- workspace carve-up (ws >= 512 MB per fill evidence; need ~110 MB) ----
    char* p = (char*)d_ws;
    auto alloc_f = [&](size_t n) { float* r = (float*)p; p += n * 4; return r; };
    auto alloc_h = [&](size_t n) { u16* r = (u16*)p; p += ((n * 2 + 15) & ~15ull); return r; };

    float* qbuf   = alloc_f((size_t)B_SZ * 256);
    float* cbar   = alloc_f((size_t)B_SZ * 256);
    float* rnn_in = alloc_f((size_t)B_SZ * 384);
    float* gxc    = alloc_f((size_t)B_SZ * 1536);
    float* ghc    = alloc_f((size_t)B_SZ * 1536);
    u16* rin_hi = alloc_h((size_t)B_SZ * 384);
    u16* rin_lo = alloc_h((size_t)B_SZ * 384);
    u16* hp_hi  = alloc_h((size_t)2 * B_SZ * 512);
    u16* hp_lo  = alloc_h((size_t)2 * B_SZ * 512);
    u16* h0_hi  = alloc_h((size_t)B_SZ * 512);
    u16* h0_lo  = alloc_h((size_t)B_SZ * 512);
    u16* W0x_hi = alloc_h((size_t)1536 * 384);
    u16* W0x_lo = alloc_h((size_t)1536 * 384);
    u16* W0h_hi = alloc_h((size_t)1536 * 512);
    u16* W0h_lo = alloc_h((size_t)1536 * 512);
    u16* W1x_hi = alloc_h((size_t)1536 * 512);
    u16* W1x_lo = alloc_h((size_t)1536 * 512);
    u16* W1h_hi = alloc_h((size_t)1536 * 512);
    u16* W1h_lo = alloc_h((size_t)1536 * 512);
    float* b0x = alloc_f(1536);
    float* b0h = alloc_f(1536);
    float* b1x = alloc_f(1536);
    float* b1h = alloc_f(1536);

    // ---- weight prep (independent of activations) ----
    transpose_split_w<<<dim3(24, 6), 256, 0, stream>>>(i2hW0, hWW0, 1024, 512, 384, W0x_hi, W0x_lo);
    transpose_split_w<<<dim3(24, 8), 256, 0, stream>>>(h2hW0, hUW0, 1024, 512, 512, W0h_hi, W0h_lo);
    transpose_split_w<<<dim3(24, 8), 256, 0, stream>>>(i2hW1, hWW1, 1024, 512, 512, W1x_hi, W1x_lo);
    transpose_split_w<<<dim3(24, 8), 256, 0, stream>>>(h2hW1, hUW1, 1024, 512, 512, W1h_hi, W1h_lo);
    bias_cat_kernel<<<6, 256, 0, stream>>>(i2hb0, hWb0, 1024, 1536, b0x);
    bias_cat_kernel<<<6, 256, 0, stream>>>(h2hb0, hUb0, 1024, 1536, b0h);
    bias_cat_kernel<<<6, 256, 0, stream>>>(i2hb1, hWb1, 1024, 1536, b1x);
    bias_cat_kernel<<<6, 256, 0, stream>>>(h2hb1, hUb1, 1024, 1536, b1h);
    // prev_hidden split (both cells at once; ph contiguous)
    split_act_kernel<<<(2 * B_SZ * 512 / 4 + 255) / 256, 256, 0, stream>>>(ph, hp_hi, hp_lo, 2 * B_SZ * 512 / 4);

    // ---- attention ----
    gemm_bt64_kernel<<<dim3(4, 64), 256, 0, stream>>>(snd, Wk, qbuf, B_SZ, 256, 128, 256);
    attn_ctx_kernel<<<B_SZ, 256, 0, stream>>>(co, qbuf, snd, pmsg, cbar, rnn_in);
    gemm_ctx_kernel<<<dim3(2, 32), 256, 0, stream>>>(cbar, Wk, bk, rnn_in, B_SZ, 128, 256, 384);
    split_act_kernel<<<(B_SZ * 384 / 4 + 255) / 256, 256, 0, stream>>>(rnn_in, rin_hi, rin_lo, B_SZ * 384 / 4);

    // ---- GRU cell 0 ----
    mfma_gemm_kernel<<<dim3(12, 32), 256, 0, stream>>>(rin_hi, rin_lo, W0x_hi, W0x_lo, b0x, gxc, B_SZ, 1536, 384);
    mfma_gemm_kernel<<<dim3(12, 32), 256, 0, stream>>>(hp_hi, hp_lo, W0h_hi, W0h_lo, b0h, ghc, B_SZ, 1536, 512);
    gru_combine_kernel<<<B_SZ, 256, 0, stream>>>(gxc, ghc, h0prev, h0out);
    split_act_kernel<<<(B_SZ * 512 / 4 + 255) / 256, 256, 0, stream>>>(h0out, h0_hi, h0_lo, B_SZ * 512 / 4);

    // ---- GRU cell 1 ----
    mfma_gemm_kernel<<<dim3(12, 32), 256, 0, stream>>>(h0_hi, h0_lo, W1x_hi, W1x_lo, b1x, gxc, B_SZ, 1536, 512);
    mfma_gemm_kernel<<<dim3(12, 32), 256, 0, stream>>>(hp_hi + (size_t)B_SZ * 512, hp_lo + (size_t)B_SZ * 512,
                                                      W1h_hi, W1h_lo, b1h, ghc, B_SZ, 1536, 512);
    gru_combine_kernel<<<B_SZ, 256, 0, stream>>>(gxc, ghc, h1prev, h1out);

    // ---- output head ----
    out_kernel<<<B_SZ / 4, 256, 0, stream>>>(h1out, outW, outb, out);
}